// Round 6
// baseline (276.267 us; speedup 1.0000x reference)
//
#include <hip/hip_runtime.h>
#include <cstddef>

#define B   2
#define S   1024
#define PP  1024          // start_pos
#define CTX 2048
#define E   2048
#define H   32
#define KVH 8
#define HD  64
#define GQ  4             // H / KVH
#define NQKV 3072         // E + 2*KVH*HD

typedef short s4v  __attribute__((ext_vector_type(4)));
typedef short s8v  __attribute__((ext_vector_type(8)));
typedef float f4v  __attribute__((ext_vector_type(4)));

__device__ __forceinline__ short f2bf(float f) {   // RNE f32 -> bf16
  union { float f; unsigned u; } v; v.f = f;
  unsigned r = v.u + 0x7fffu + ((v.u >> 16) & 1u);
  return (short)(r >> 16);
}
__device__ __forceinline__ float bf2f(short h) {
  union { unsigned u; float f; } v; v.u = ((unsigned)(unsigned short)h) << 16;
  return v.f;
}

__device__ __forceinline__ void gl_lds16(const void* g, void* l) {
  // async 16B/lane global->LDS; LDS dest = wave-uniform base + lane*16
  __builtin_amdgcn_global_load_lds((const __attribute__((address_space(1))) unsigned*)g,
                                   (__attribute__((address_space(3))) unsigned*)l, 16, 0, 0);
}

// ---------------------------------------------------------------------------
// prep: all f32->bf16 converts + cache_k copy + V^T(old) + zero(out).
// Grid partitioned by blockIdx.x:
//   [0,2048) x | [2048,4096) Wq | [4096,4608) Wk | [4608,5120) Wv
//   [5120,7168) Wo | [7168,7680) cache_k | [7680,7936) vT_old | [7936,8960) zero out
// ---------------------------------------------------------------------------
__global__ __launch_bounds__(256) void prep(const float* __restrict__ x,
                                            const float* __restrict__ Wq,
                                            const float* __restrict__ Wk,
                                            const float* __restrict__ Wv,
                                            const float* __restrict__ Wo,
                                            const float* __restrict__ ck,
                                            const float* __restrict__ cv,
                                            short* __restrict__ xb,
                                            short* __restrict__ wqkv,
                                            short* __restrict__ wob,
                                            short* __restrict__ keys,
                                            short* __restrict__ vt,
                                            float4* __restrict__ outz) {
  __shared__ short Ts[64][72];
  const int blk = blockIdx.x, tid = threadIdx.x;
  if (blk < 7168) {
    const float* s; short* d; int base;
    if (blk < 2048)      { s = x;  d = xb;             base = blk; }
    else if (blk < 4096) { s = Wq; d = wqkv;           base = blk - 2048; }
    else if (blk < 4608) { s = Wk; d = wqkv + 4194304; base = blk - 4096; }
    else if (blk < 5120) { s = Wv; d = wqkv + 5242880; base = blk - 4608; }
    else                 { s = Wo; d = wob;            base = blk - 5120; }
    int i = (base * 256 + tid) * 8;
    float4 a = *(const float4*)&s[i];
    float4 b = *(const float4*)&s[i + 4];
    s8v o;
    o[0]=f2bf(a.x); o[1]=f2bf(a.y); o[2]=f2bf(a.z); o[3]=f2bf(a.w);
    o[4]=f2bf(b.x); o[5]=f2bf(b.y); o[6]=f2bf(b.z); o[7]=f2bf(b.w);
    *(s8v*)&d[i] = o;
  } else if (blk < 7680) {
    // cache_k f32 [0,PP) -> bf16 keys
    int idx = (blk - 7168) * 256 + tid;
    int bkv = idx >> 13;
    int rem = idx & 8191;
    size_t off = (size_t)bkv * (CTX * HD) + (size_t)rem * 8;
    float4 a = *(const float4*)&ck[off];
    float4 b = *(const float4*)&ck[off + 4];
    s8v o;
    o[0]=f2bf(a.x); o[1]=f2bf(a.y); o[2]=f2bf(a.z); o[3]=f2bf(a.w);
    o[4]=f2bf(b.x); o[5]=f2bf(b.y); o[6]=f2bf(b.z); o[7]=f2bf(b.w);
    *(s8v*)&keys[off] = o;
  } else if (blk < 7936) {
    // cache_v [0,PP) -> valsT (permuted key order within 64-blocks)
    const int blk2 = blk - 7680;              // B*KVH*(PP/64) = 256
    const int bkv = blk2 >> 4;
    const int p0  = (blk2 & 15) * 64;
    const float* src = cv + (size_t)bkv * CTX * HD + (size_t)p0 * HD;
    {
      int dq = tid & 15, kb = tid >> 4;
      float4 vv[4];
#pragma unroll
      for (int i = 0; i < 4; i++)
        vv[i] = *(const float4*)&src[(size_t)(kb * 4 + i) * HD + dq * 4];
#pragma unroll
      for (int j = 0; j < 4; j++) {
        s4v p;
        p[0]=f2bf(((const float*)&vv[0])[j]); p[1]=f2bf(((const float*)&vv[1])[j]);
        p[2]=f2bf(((const float*)&vv[2])[j]); p[3]=f2bf(((const float*)&vv[3])[j]);
        *(s4v*)&Ts[dq * 4 + j][kb * 4] = p;
      }
    }
    __syncthreads();
    {
      int d = tid >> 2, c = tid & 3;
      short* dst = vt + ((size_t)bkv * HD + d) * CTX + p0 + (c >> 1) * 32 + (c & 1) * 4;
#pragma unroll
      for (int j = 0; j < 4; j++) {
        s4v q4 = *(const s4v*)&Ts[d][c * 16 + j * 4];
        *(s4v*)&dst[j * 8] = q4;
      }
    }
  } else {
    // zero f32 out (4,194,304 floats) for O-proj split-K atomics
    int i0 = (blk - 7936) * 1024 + tid * 4;
#pragma unroll
    for (int j = 0; j < 4; j++) outz[i0 + j] = make_float4(0.f, 0.f, 0.f, 0.f);
  }
}

// ---------------------------------------------------------------------------
// QKV GEMM, BK=64, 2-phase double-buffered staging. Fused epilogue:
// q (bf16); K-region RoPE'd in-register -> keys; V -> permuted valsT.
// ---------------------------------------------------------------------------
__global__ __launch_bounds__(256) void qkv_gemm(const short* __restrict__ A,
                                                const short* __restrict__ Bw,
                                                const float* __restrict__ cosb,
                                                const float* __restrict__ sinb,
                                                short* __restrict__ qb,
                                                short* __restrict__ keys,
                                                short* __restrict__ vt) {
  __shared__ short As[2][8192];
  __shared__ short Bs[2][8192];
  const int tid  = threadIdx.x;
  const int wv   = tid >> 6, lane = tid & 63;
  const int wm   = wv & 1, wn = wv >> 1;
  const int n16  = lane & 15, g = lane >> 4;
  const int m0   = blockIdx.y * 128, n0 = blockIdx.x * 128;
  const int K = 2048;

  const int rr = tid >> 3;                          // 0..31 rows per stage step
  const int cc = ((tid & 7) ^ (rr & 7)) * 8;        // pre-swizzled col chunk
  const short* pA = A  + (size_t)(m0 + rr) * K + cc;
  const short* pB = Bw + (size_t)(n0 + rr) * K + cc;

  auto stage = [&](int buf, int kofs) {
#pragma unroll
    for (int st = 0; st < 4; st++) {
      gl_lds16(pA + kofs + (size_t)st * 32 * K, &As[buf][(st * 256 + wv * 64) * 8]);
      gl_lds16(pB + kofs + (size_t)st * 32 * K, &Bs[buf][(st * 256 + wv * 64) * 8]);
    }
  };

  f4v acc[4][4] = {};
  stage(0, 0);
  int cur = 0;
  for (int k0 = 0; k0 < K; k0 += 64) {
    __syncthreads();                       // buf[cur] ready (drain after compute)
    if (k0 + 64 < K) stage(cur ^ 1, k0 + 64);

#pragma unroll
    for (int kk = 0; kk < 2; kk++) {
      s8v af[4], bf[4];
#pragma unroll
      for (int mt = 0; mt < 4; mt++)
        af[mt] = *(const s8v*)&As[cur][(wm * 64 + mt * 16 + n16) * 64 + (((kk << 2) | g) ^ (n16 & 7)) * 8];
#pragma unroll
      for (int nt = 0; nt < 4; nt++)
        bf[nt] = *(const s8v*)&Bs[cur][(wn * 64 + nt * 16 + n16) * 64 + (((kk << 2) | g) ^ (n16 & 7)) * 8];
#pragma unroll
      for (int mt = 0; mt < 4; mt++)
#pragma unroll
        for (int nt = 0; nt < 4; nt++)
          acc[mt][nt] = __builtin_amdgcn_mfma_f32_16x16x32_bf16(af[mt], bf[nt], acc[mt][nt], 0, 0, 0);
    }
    cur ^= 1;
  }

  const int rowb = m0 + wm * 64 + g * 4;
  const int colb = n0 + wn * 64 + n16;
  if (n0 < 2048) {
    // Q region -> qb (B,S,E) bf16
#pragma unroll
    for (int mt = 0; mt < 4; mt++)
#pragma unroll
      for (int nt = 0; nt < 4; nt++) {
        size_t base = (size_t)(rowb + mt * 16) * E + colb + nt * 16;
#pragma unroll
        for (int r = 0; r < 4; r++)
          qb[base + (size_t)r * E] = f2bf(acc[mt][nt][r]);
      }
  } else if (n0 < 2560) {
    // K region: RoPE in-register (f32), scatter into keys at pos PP+s.
    const int kvh = ((n0 - 2048) >> 6) + wn;
#pragma unroll
    for (int mt = 0; mt < 4; mt++) {
      const int row = rowb + mt * 16;          // in [0, B*S)
      const int bb = row >> 10, s = row & 1023;
      const float* crow = cosb + ((size_t)bb * S + s) * HD;
      const float* srow = sinb + ((size_t)bb * S + s) * HD;
      const size_t kdst = (((size_t)bb * KVH + kvh) * CTX + PP + s) * HD;
#pragma unroll
      for (int nt = 0; nt < 2; nt++) {
        const int d = n16 + nt * 16;
#pragma unroll
        for (int r = 0; r < 4; r++) {
          float c  = crow[r * HD + d];
          float sn = srow[r * HD + d];
          float k1 = acc[mt][nt][r], k2 = acc[mt][nt + 2][r];
          keys[kdst + (size_t)r * HD + d]      = f2bf(k1 * c - k2 * sn);
          keys[kdst + (size_t)r * HD + d + 32] = f2bf(k2 * c + k1 * sn);
        }
      }
    }
  } else {
    // V region -> valsT[(bkv*HD+d)*CTX + PP + perm(s)]
    const int b    = m0 >> 10;
    const int head = ((n0 - 2560) >> 6) + wn;
    const int sbase = (m0 - (b << 10)) + wm * 64;   // multiple of 64
    const size_t vrowb = (size_t)(b * KVH + head) * HD;
#pragma unroll
    for (int mt = 0; mt < 4; mt++) {
      const int pos = PP + sbase + ((mt >> 1) << 5) + ((mt & 1) << 2) + (g << 3);
#pragma unroll
      for (int nt = 0; nt < 4; nt++) {
        const int d = nt * 16 + n16;
        s4v o;
        o[0] = f2bf(acc[mt][nt][0]); o[1] = f2bf(acc[mt][nt][1]);
        o[2] = f2bf(acc[mt][nt][2]); o[3] = f2bf(acc[mt][nt][3]);
        *(s4v*)&vt[(vrowb + d) * CTX + pos] = o;
      }
    }
  }
}

// ---------------------------------------------------------------------------
// bf16 MFMA GEMM, BK=64, 2-phase double-buffered staging, split-K=2,
// atomic f32 accumulate (for O-proj).
// ---------------------------------------------------------------------------
__global__ __launch_bounds__(256) void gemm_bf16_sk(const short* __restrict__ A,
                                                    const short* __restrict__ Bw,
                                                    float* __restrict__ C,
                                                    int M, int N, int K) {
  __shared__ short As[2][8192];
  __shared__ short Bs[2][8192];
  const int tid  = threadIdx.x;
  const int wv   = tid >> 6, lane = tid & 63;
  const int wm   = wv & 1, wn = wv >> 1;
  const int n16  = lane & 15, g = lane >> 4;
  const int m0   = blockIdx.y * 128, n0 = blockIdx.x * 128;
  const int kh   = K >> 1;
  const int kbeg = blockIdx.z * kh;

  const int rr = tid >> 3;
  const int cc = ((tid & 7) ^ (rr & 7)) * 8;
  const short* pA = A  + (size_t)(m0 + rr) * K + kbeg + cc;
  const short* pB = Bw + (size_t)(n0 + rr) * K + kbeg + cc;

  auto stage = [&](int buf, int kofs) {
#pragma unroll
    for (int st = 0; st < 4; st++) {
      gl_lds16(pA + kofs + (size_t)st * 32 * K, &As[buf][(st * 256 + wv * 64) * 8]);
      gl_lds16(pB + kofs + (size_t)st * 32 * K, &Bs[buf][(st * 256 + wv * 64) * 8]);
    }
  };

  f4v acc[4][4] = {};
  stage(0, 0);
  int cur = 0;
  for (int k0 = 0; k0 < kh; k0 += 64) {
    __syncthreads();
    if (k0 + 64 < kh) stage(cur ^ 1, k0 + 64);

#pragma unroll
    for (int kk = 0; kk < 2; kk++) {
      s8v af[4], bf[4];
#pragma unroll
      for (int mt = 0; mt < 4; mt++)
        af[mt] = *(const s8v*)&As[cur][(wm * 64 + mt * 16 + n16) * 64 + (((kk << 2) | g) ^ (n16 & 7)) * 8];
#pragma unroll
      for (int nt = 0; nt < 4; nt++)
        bf[nt] = *(const s8v*)&Bs[cur][(wn * 64 + nt * 16 + n16) * 64 + (((kk << 2) | g) ^ (n16 & 7)) * 8];
#pragma unroll
      for (int mt = 0; mt < 4; mt++)
#pragma unroll
        for (int nt = 0; nt < 4; nt++)
          acc[mt][nt] = __builtin_amdgcn_mfma_f32_16x16x32_bf16(af[mt], bf[nt], acc[mt][nt], 0, 0, 0);
    }
    cur ^= 1;
  }

#pragma unroll
  for (int mt = 0; mt < 4; mt++)
#pragma unroll
    for (int nt = 0; nt < 4; nt++) {
      size_t base = (size_t)(m0 + wm * 64 + mt * 16 + g * 4) * N + n0 + wn * 64 + nt * 16 + n16;
#pragma unroll
      for (int r = 0; r < 4; r++)
        unsafeAtomicAdd(&C[base + (size_t)r * N], acc[mt][nt][r]);
    }
}

// ---------------------------------------------------------------------------
// MFMA flash attention v3: ctx-split waves, wave-private LDS, NO barriers in
// the main loop. Block = 64 q-rows of (b,h,sblk); wave w owns 32-key tiles
// k0 = w*32 + i*128 and computes partial O,l over ALL 64 q-rows (additive
// because softmax uses fixed zero bias — partials merge by summation).
// Per tile per wave: 8 gl_lds stage -> counted s_waitcnt vmcnt(8) (wave-level
// T4 pipeline, dbuf) -> 8 ds_read_b128 -> 32 MFMA (4:1 vs old 1:1).
// End: 3-barrier LDS merge (O via 2 x 17KB f32 bufs reusing staging, l via
// small array), normalize, store.
// ---------------------------------------------------------------------------
__global__ __launch_bounds__(256) void attn_mfma(const short* __restrict__ qb,
                                                 const float* __restrict__ cosb,
                                                 const float* __restrict__ sinb,
                                                 const short* __restrict__ keys,
                                                 const short* __restrict__ valsT,
                                                 short* __restrict__ attn) {
  __shared__ short stg[32768];       // 64KB: wave w region = stg + w*8192;
                                     // buf c: +c*4096 (K 2048 shorts, V^T 2048)
  __shared__ float l_lds[4][64];

  const int sblk = 15 - (blockIdx.x & 15);     // long blocks first
  const int h    = (blockIdx.x >> 4) & (H - 1);
  const int b    = blockIdx.x >> 9;
  const int kv   = h >> 2;
  const int sq0  = sblk * 64;
  const int kend = PP + sq0 + 64;              // keys for this block
  const int qminb = PP + sq0;                  // block's min query position

  const int tid  = threadIdx.x;
  const int w    = tid >> 6;
  const int lane = tid & 63;
  const int n    = lane & 15;
  const int g    = lane >> 4;

  const short* kbase = keys  + ((size_t)b * KVH + kv) * CTX * HD;
  const short* vtb   = valsT + ((size_t)b * KVH + kv) * (size_t)HD * CTX;

  // ---- Q frags for ALL 4 q-groups (64 rows): RoPE fused, scale=0.125*log2e
  s8v qlo[4], qhi[4];
#pragma unroll
  for (int qg = 0; qg < 4; qg++) {
    const size_t row = (size_t)b * S + sq0 + qg * 16 + n;
    const short* qrow = qb + row * E + h * 64;
    const float* crow = cosb + row * HD;
    const float* srow = sinb + row * HD;
    const float SC = 0.18033688011112042f;   // 0.125 * log2(e)
    s8v q0 = *(const s8v*)&qrow[g * 8];
    s8v q1 = *(const s8v*)&qrow[32 + g * 8];
    float cc[8], ss[8];
    *(float4*)&cc[0] = *(const float4*)&crow[g * 8];
    *(float4*)&cc[4] = *(const float4*)&crow[g * 8 + 4];
    *(float4*)&ss[0] = *(const float4*)&srow[g * 8];
    *(float4*)&ss[4] = *(const float4*)&srow[g * 8 + 4];
#pragma unroll
    for (int j = 0; j < 8; j++) {
      float fl = bf2f(q0[j]), fh = bf2f(q1[j]);
      qlo[qg][j] = f2bf((fl * cc[j] - fh * ss[j]) * SC);
      qhi[qg][j] = f2bf((fh * cc[j] + fl * ss[j]) * SC);
    }
  }
  __builtin_amdgcn_sched_barrier(0);   // pin Q loads before staging (vmcnt count)

  f4v O[4][4] = {};                    // [qg][dg]; q=qg*16+n, d=dg*16+g*4+r
  float la[4] = {0.f, 0.f, 0.f, 0.f};  // per-qg l partials

  // staging addresses (wave-private tiles, chunk-XOR pre-swizzled source)
  const int krj = lane >> 3;                       // K: 8 rows/call
  const int kcj = ((lane & 7) ^ (krj & 7)) * 8;    //    8 chunks of 16B
  const short* kg = kbase + (size_t)krj * HD + kcj;
  const int vrj = lane >> 2;                       // V: 16 d-rows/call
  const int vcj = ((lane & 3) ^ (vrj & 3)) * 8;    //    4 chunks of 16B
  const short* vg = vtb + (size_t)vrj * CTX + vcj;
  short* const wreg = stg + w * 8192;

  auto stage = [&](int c, int k0) {
    short* kd = wreg + c * 4096;
    short* vd = kd + 2048;
#pragma unroll
    for (int j = 0; j < 4; j++)
      gl_lds16(kg + (size_t)(k0 + j * 8) * HD, kd + j * 512);
#pragma unroll
    for (int j = 0; j < 4; j++)
      gl_lds16(vg + (size_t)(j * 16) * CTX + k0, vd + j * 512);
  };

  const int xk = (g ^ (n & 7)) * 8;    // K frag lo chunk (swizzled); hi = ^32
  const int xv = (g ^ (n & 3)) * 8;    // V frag chunk (swizzled)

  stage(0, w * 32);
  int cur = 0;
  for (int k0 = w * 32; k0 < kend; k0 += 128) {
    const bool pf = (k0 + 128 < kend);
    if (pf) stage(cur ^ 1, k0 + 128);
    if (pf) asm volatile("s_waitcnt vmcnt(8)" ::: "memory");
    else    asm volatile("s_waitcnt vmcnt(0)" ::: "memory");
    __builtin_amdgcn_sched_barrier(0);

    const short* kb = wreg + cur * 4096;
    const short* vb = kb + 2048;

    // ---- S^T = K_tile(32 keys) @ Q^T for all 4 q-groups ----
    f4v sc[2][4];
#pragma unroll
    for (int st = 0; st < 2; st++) {
      const short* krow = kb + (st * 16 + n) * 64;
      s8v alo = *(const s8v*)(krow + xk);
      s8v ahi = *(const s8v*)(krow + (xk ^ 32));
#pragma unroll
      for (int qg = 0; qg < 4; qg++) {
        f4v z = {0.f, 0.f, 0.f, 0.f};
        z = __builtin_amdgcn_mfma_f32_16x16x32_bf16(alo, qlo[qg], z, 0, 0, 0);
        sc[st][qg] = __builtin_amdgcn_mfma_f32_16x16x32_bf16(ahi, qhi[qg], z, 0, 0, 0);
      }
    }

    // ---- causal mask (only the 2 diagonal 32-tiles of the block) ----
    if (k0 + 31 > qminb) {
#pragma unroll
      for (int st = 0; st < 2; st++)
#pragma unroll
        for (int qg = 0; qg < 4; qg++)
#pragma unroll
          for (int r = 0; r < 4; r++) {
            int kpos = k0 + st * 16 + g * 4 + r;
            if (kpos > qminb + qg * 16 + n) sc[st][qg][r] = -3e38f;
          }
    }

    // ---- exp2 softmax; P packed per qg (slot = g*8 + st*4 + r) ----
    union pu { unsigned u[4]; s8v v; } pb[4];
#pragma unroll
    for (int qg = 0; qg < 4; qg++) {
      float e0 = __builtin_amdgcn_exp2f(sc[0][qg][0]);
      float e1 = __builtin_amdgcn_exp2f(sc[0][qg][1]);
      float e2 = __builtin_amdgcn_exp2f(sc[0][qg][2]);
      float e3 = __builtin_amdgcn_exp2f(sc[0][qg][3]);
      float e4 = __builtin_amdgcn_exp2f(sc[1][qg][0]);
      float e5 = __builtin_amdgcn_exp2f(sc[1][qg][1]);
      float e6 = __builtin_amdgcn_exp2f(sc[1][qg][2]);
      float e7 = __builtin_amdgcn_exp2f(sc[1][qg][3]);
      la[qg] += ((e0 + e1) + (e2 + e3)) + ((e4 + e5) + (e6 + e7));
      unsigned w0, w1, w2, w3;
      asm("v_cvt_pk_bf16_f32 %0, %1, %2" : "=v"(w0) : "v"(e0), "v"(e1));
      asm("v_cvt_pk_bf16_f32 %0, %1, %2" : "=v"(w1) : "v"(e2), "v"(e3));
      asm("v_cvt_pk_bf16_f32 %0, %1, %2" : "=v"(w2) : "v"(e4), "v"(e5));
      asm("v_cvt_pk_bf16_f32 %0, %1, %2" : "=v"(w3) : "v"(e6), "v"(e7));
      pb[qg].u[0] = w0; pb[qg].u[1] = w1; pb[qg].u[2] = w2; pb[qg].u[3] = w3;
    }

    // ---- O^T += V^T(32 keys) @ P : K-dim-32 MFMA, 1 V read per dg ----
#pragma unroll
    for (int dg = 0; dg < 4; dg++) {
      s8v va = *(const s8v*)(vb + (dg * 16 + n) * 32 + xv);
#pragma unroll
      for (int qg = 0; qg < 4; qg++)
        O[qg][dg] = __builtin_amdgcn_mfma_f32_16x16x32_bf16(va, pb[qg].v, O[qg][dg], 0, 0, 0);
    }
    cur ^= 1;
  }

  // ---- per-wave l: reduce over g, publish ----
#pragma unroll
  for (int qg = 0; qg < 4; qg++) {
    float l = la[qg];
    l += __shfl_xor(l, 16);
    l += __shfl_xor(l, 32);
    if (g == 0) l_lds[w][qg * 16 + n] = l;
  }
  __syncthreads();                    // all waves done; stg reusable as f32

  // ---- O merge: bufA = w0 + w2, bufB = w1 + w3 (stride 68 to dodge banks) --
  float* mb  = (float*)stg;
  float* bufA = mb;                   // 64*68 = 4352 floats
  float* bufB = mb + 4352;
  if (w < 2) {
    float* dst = (w == 0) ? bufA : bufB;
#pragma unroll
    for (int qg = 0; qg < 4; qg++)
#pragma unroll
      for (int dg = 0; dg < 4; dg++)
        *(f4v*)&dst[(qg * 16 + n) * 68 + dg * 16 + g * 4] = O[qg][dg];
  }
  __syncthreads();
  if (w >= 2) {
    float* dst = (w == 2) ? bufA : bufB;
#pragma unroll
    for (int qg = 0; qg < 4; qg++)
#pragma unroll
      for (int dg = 0; dg < 4; dg++) {
        float* p = &dst[(qg * 16 + n) * 68 + dg * 16 + g * 4];
        f4v t = *(f4v*)p;
        t += O[qg][dg];
        *(f4v*)p = t;
      }
  }
  __syncthreads();

  // ---- final: wave w stores q-rows [w*16, w*16+16) ----
  const int q = w * 16 + n;
  const float rl = 1.f / (l_lds[0][q] + l_lds[1][q] + l_lds[2][q] + l_lds[3][q]);
  short* orow = attn + ((size_t)b * S + sq0 + q) * E + h * 64;
#pragma unroll
  for (int dg = 0; dg < 4; dg++) {
    f4v a = *(const f4v*)&bufA[q * 68 + dg * 16 + g * 4];
    f4v c = *(const f4v*)&bufB[q * 68 + dg * 16 + g * 4];
    s4v o;
    o[0] = f2bf((a[0] + c[0]) * rl); o[1] = f2bf((a[1] + c[1]) * rl);
    o[2] = f2bf((a[2] + c[2]) * rl); o[3] = f2bf((a[3] + c[3]) * rl);
    *(s4v*)&orow[dg * 16 + g * 4] = o;
  }
}

// ---------------------------------------------------------------------------
extern "C" void kernel_launch(void* const* d_in, const int* in_sizes, int n_in,
                              void* d_out, int out_size, void* d_ws, size_t ws_size,
                              hipStream_t stream) {
  const float* x       = (const float*)d_in[0];
  const float* cosb    = (const float*)d_in[1];
  const float* sinb    = (const float*)d_in[2];
  const float* cache_k = (const float*)d_in[4];
  const float* cache_v = (const float*)d_in[5];
  const float* Wq      = (const float*)d_in[6];
  const float* Wk      = (const float*)d_in[7];
  const float* Wv      = (const float*)d_in[8];
  const float* Wo      = (const float*)d_in[9];
  float* out = (float*)d_out;

  short* xb    = (short*)d_ws;                 // 4,194,304
  short* wqkv  = xb + 4194304;                 // 6,291,456
  short* wob   = wqkv + 6291456;               // 4,194,304
  short* keysb = wob + 4194304;                // 2,097,152
  short* valsT = keysb + 2097152;              // 2,097,152 (permuted V^T)
  short* aout  = valsT + 2097152;              // 4,194,304
  short* qb    = aout + 4194304;               // 4,194,304  (~55 MB total)

  dim3 blk(256);

  // 1) all converts + cache_k + vT_old + zero(out)
  prep<<<8960, blk, 0, stream>>>(x, Wq, Wk, Wv, Wo, cache_k, cache_v,
                                 xb, wqkv, wob, keysb, valsT, (float4*)out);

  // 2) fused QKV projection: q bf16 / K RoPE'd into keys / valsT direct
  qkv_gemm<<<dim3(NQKV / 128, (B * S) / 128), blk, 0, stream>>>(xb, wqkv, cosb, sinb,
                                                                qb, keysb, valsT);

  // 3) attention v3 (ctx-split waves, barrier-free main loop) -> bf16 (B,S,E)
  attn_mfma<<<B * H * (S / 64), blk, 0, stream>>>(qb, cosb, sinb, keysb, valsT, aout);

  // 4) output projection, split-K=2 -> f32 out (zeroed in prep)
  gemm_bf16_sk<<<dim3(E / 128, (B * S) / 128, 2), blk, 0, stream>>>(aout, wob, out, B * S, E, E);
}

// Round 7
// 252.955 us; speedup vs baseline: 1.0922x; 1.0922x over previous
//
#include <hip/hip_runtime.h>
#include <cstddef>

#define B   2
#define S   1024
#define PP  1024          // start_pos
#define CTX 2048
#define E   2048
#define H   32
#define KVH 8
#define HD  64
#define GQ  4             // H / KVH
#define NQKV 3072         // E + 2*KVH*HD

typedef short s4v  __attribute__((ext_vector_type(4)));
typedef short s8v  __attribute__((ext_vector_type(8)));
typedef float f4v  __attribute__((ext_vector_type(4)));

__device__ __forceinline__ short f2bf(float f) {   // RNE f32 -> bf16
  union { float f; unsigned u; } v; v.f = f;
  unsigned r = v.u + 0x7fffu + ((v.u >> 16) & 1u);
  return (short)(r >> 16);
}
__device__ __forceinline__ float bf2f(short h) {
  union { unsigned u; float f; } v; v.u = ((unsigned)(unsigned short)h) << 16;
  return v.f;
}

__device__ __forceinline__ void gl_lds16(const void* g, void* l) {
  // async 16B/lane global->LDS; LDS dest = wave-uniform base + lane*16
  __builtin_amdgcn_global_load_lds((const __attribute__((address_space(1))) unsigned*)g,
                                   (__attribute__((address_space(3))) unsigned*)l, 16, 0, 0);
}

// ---------------------------------------------------------------------------
// prep: only the sections qkv_gemm DEPENDS on (x + Wq/Wk/Wv converts).
// [0,2048) x | [2048,4096) Wq | [4096,4608) Wk | [4608,5120) Wv
// The attn/oproj-only sections (Wo, cache_k, vT_old, zero-out) ride along
// inside qkv_gemm's grid (aux blocks) to fill CUs idle during the GEMM.
// ---------------------------------------------------------------------------
__global__ __launch_bounds__(256) void prep(const float* __restrict__ x,
                                            const float* __restrict__ Wq,
                                            const float* __restrict__ Wk,
                                            const float* __restrict__ Wv,
                                            short* __restrict__ xb,
                                            short* __restrict__ wqkv) {
  const int blk = blockIdx.x, tid = threadIdx.x;
  const float* s; short* d; int base;
  if (blk < 2048)      { s = x;  d = xb;             base = blk; }
  else if (blk < 4096) { s = Wq; d = wqkv;           base = blk - 2048; }
  else if (blk < 4608) { s = Wk; d = wqkv + 4194304; base = blk - 4096; }
  else                 { s = Wv; d = wqkv + 5242880; base = blk - 4608; }
  int i = (base * 256 + tid) * 8;
  float4 a = *(const float4*)&s[i];
  float4 b = *(const float4*)&s[i + 4];
  s8v o;
  o[0]=f2bf(a.x); o[1]=f2bf(a.y); o[2]=f2bf(a.z); o[3]=f2bf(a.w);
  o[4]=f2bf(b.x); o[5]=f2bf(b.y); o[6]=f2bf(b.z); o[7]=f2bf(b.w);
  *(s8v*)&d[i] = o;
}

// ---------------------------------------------------------------------------
// QKV GEMM (ids [0,384)) + aux prep blocks (ids [384,4224)).
// GEMM: BK=64, 2-phase dbuf staging, fused epilogue (q bf16; K RoPE'd
// in-register -> keys; V -> permuted valsT).
// Aux: [0,2048) Wo convert | [2048,2560) cache_k | [2560,2816) vT_old |
//      [2816,3840) zero out. These fill CUs idle during the 384-block GEMM.
// ---------------------------------------------------------------------------
__global__ __launch_bounds__(256) void qkv_gemm(const short* __restrict__ A,
                                                const short* __restrict__ Bw,
                                                const float* __restrict__ cosb,
                                                const float* __restrict__ sinb,
                                                const float* __restrict__ Wo,
                                                const float* __restrict__ ck,
                                                const float* __restrict__ cv,
                                                short* __restrict__ qb,
                                                short* __restrict__ keys,
                                                short* __restrict__ vt,
                                                short* __restrict__ wob,
                                                float4* __restrict__ outz) {
  __shared__ short As[2][8192];
  __shared__ short Bs[2][8192];
  const int tid = threadIdx.x;
  const int id  = blockIdx.x;

  if (id >= 384) {                     // ---------- aux prep blocks ----------
    const int aux = id - 384;
    if (aux < 2048) {
      // Wo f32 -> bf16
      int i = (aux * 256 + tid) * 8;
      float4 a = *(const float4*)&Wo[i];
      float4 b = *(const float4*)&Wo[i + 4];
      s8v o;
      o[0]=f2bf(a.x); o[1]=f2bf(a.y); o[2]=f2bf(a.z); o[3]=f2bf(a.w);
      o[4]=f2bf(b.x); o[5]=f2bf(b.y); o[6]=f2bf(b.z); o[7]=f2bf(b.w);
      *(s8v*)&wob[i] = o;
    } else if (aux < 2560) {
      // cache_k f32 [0,PP) -> bf16 keys
      int idx = (aux - 2048) * 256 + tid;
      int bkv = idx >> 13;
      int rem = idx & 8191;
      size_t off = (size_t)bkv * (CTX * HD) + (size_t)rem * 8;
      float4 a = *(const float4*)&ck[off];
      float4 b = *(const float4*)&ck[off + 4];
      s8v o;
      o[0]=f2bf(a.x); o[1]=f2bf(a.y); o[2]=f2bf(a.z); o[3]=f2bf(a.w);
      o[4]=f2bf(b.x); o[5]=f2bf(b.y); o[6]=f2bf(b.z); o[7]=f2bf(b.w);
      *(s8v*)&keys[off] = o;
    } else if (aux < 2816) {
      // cache_v [0,PP) -> valsT (permuted key order within 64-blocks)
      short (*Ts)[72] = (short (*)[72])&As[0][0];   // reuse GEMM LDS
      const int blk2 = aux - 2560;              // B*KVH*(PP/64) = 256
      const int bkv = blk2 >> 4;
      const int p0  = (blk2 & 15) * 64;
      const float* src = cv + (size_t)bkv * CTX * HD + (size_t)p0 * HD;
      {
        int dq = tid & 15, kb = tid >> 4;
        float4 vv[4];
#pragma unroll
        for (int i = 0; i < 4; i++)
          vv[i] = *(const float4*)&src[(size_t)(kb * 4 + i) * HD + dq * 4];
#pragma unroll
        for (int j = 0; j < 4; j++) {
          s4v p;
          p[0]=f2bf(((const float*)&vv[0])[j]); p[1]=f2bf(((const float*)&vv[1])[j]);
          p[2]=f2bf(((const float*)&vv[2])[j]); p[3]=f2bf(((const float*)&vv[3])[j]);
          *(s4v*)&Ts[dq * 4 + j][kb * 4] = p;
        }
      }
      __syncthreads();
      {
        int d = tid >> 2, c = tid & 3;
        short* dst = vt + ((size_t)bkv * HD + d) * CTX + p0 + (c >> 1) * 32 + (c & 1) * 4;
#pragma unroll
        for (int j = 0; j < 4; j++) {
          s4v q4 = *(const s4v*)&Ts[d][c * 16 + j * 4];
          *(s4v*)&dst[j * 8] = q4;
        }
      }
    } else {
      // zero f32 out (4,194,304 floats) for O-proj split-K atomics
      int i0 = (aux - 2816) * 1024 + tid * 4;
#pragma unroll
      for (int j = 0; j < 4; j++) outz[i0 + j] = make_float4(0.f, 0.f, 0.f, 0.f);
    }
    return;
  }

  // ------------------------------ GEMM blocks ------------------------------
  const int wv   = tid >> 6, lane = tid & 63;
  const int wm   = wv & 1, wn = wv >> 1;
  const int n16  = lane & 15, g = lane >> 4;
  const int m0   = (id / 24) * 128, n0 = (id % 24) * 128;
  const int K = 2048;

  const int rr = tid >> 3;                          // 0..31 rows per stage step
  const int cc = ((tid & 7) ^ (rr & 7)) * 8;        // pre-swizzled col chunk
  const short* pA = A  + (size_t)(m0 + rr) * K + cc;
  const short* pB = Bw + (size_t)(n0 + rr) * K + cc;

  auto stage = [&](int buf, int kofs) {
#pragma unroll
    for (int st = 0; st < 4; st++) {
      gl_lds16(pA + kofs + (size_t)st * 32 * K, &As[buf][(st * 256 + wv * 64) * 8]);
      gl_lds16(pB + kofs + (size_t)st * 32 * K, &Bs[buf][(st * 256 + wv * 64) * 8]);
    }
  };

  f4v acc[4][4] = {};
  stage(0, 0);
  int cur = 0;
  for (int k0 = 0; k0 < K; k0 += 64) {
    __syncthreads();                       // buf[cur] ready (drain after compute)
    if (k0 + 64 < K) stage(cur ^ 1, k0 + 64);

#pragma unroll
    for (int kk = 0; kk < 2; kk++) {
      s8v af[4], bf[4];
#pragma unroll
      for (int mt = 0; mt < 4; mt++)
        af[mt] = *(const s8v*)&As[cur][(wm * 64 + mt * 16 + n16) * 64 + (((kk << 2) | g) ^ (n16 & 7)) * 8];
#pragma unroll
      for (int nt = 0; nt < 4; nt++)
        bf[nt] = *(const s8v*)&Bs[cur][(wn * 64 + nt * 16 + n16) * 64 + (((kk << 2) | g) ^ (n16 & 7)) * 8];
#pragma unroll
      for (int mt = 0; mt < 4; mt++)
#pragma unroll
        for (int nt = 0; nt < 4; nt++)
          acc[mt][nt] = __builtin_amdgcn_mfma_f32_16x16x32_bf16(af[mt], bf[nt], acc[mt][nt], 0, 0, 0);
    }
    cur ^= 1;
  }

  const int rowb = m0 + wm * 64 + g * 4;
  const int colb = n0 + wn * 64 + n16;
  if (n0 < 2048) {
    // Q region -> qb (B,S,E) bf16
#pragma unroll
    for (int mt = 0; mt < 4; mt++)
#pragma unroll
      for (int nt = 0; nt < 4; nt++) {
        size_t base = (size_t)(rowb + mt * 16) * E + colb + nt * 16;
#pragma unroll
        for (int r = 0; r < 4; r++)
          qb[base + (size_t)r * E] = f2bf(acc[mt][nt][r]);
      }
  } else if (n0 < 2560) {
    // K region: RoPE in-register (f32), scatter into keys at pos PP+s.
    const int kvh = ((n0 - 2048) >> 6) + wn;
#pragma unroll
    for (int mt = 0; mt < 4; mt++) {
      const int row = rowb + mt * 16;          // in [0, B*S)
      const int bb = row >> 10, s = row & 1023;
      const float* crow = cosb + ((size_t)bb * S + s) * HD;
      const float* srow = sinb + ((size_t)bb * S + s) * HD;
      const size_t kdst = (((size_t)bb * KVH + kvh) * CTX + PP + s) * HD;
#pragma unroll
      for (int nt = 0; nt < 2; nt++) {
        const int d = n16 + nt * 16;
#pragma unroll
        for (int r = 0; r < 4; r++) {
          float c  = crow[r * HD + d];
          float sn = srow[r * HD + d];
          float k1 = acc[mt][nt][r], k2 = acc[mt][nt + 2][r];
          keys[kdst + (size_t)r * HD + d]      = f2bf(k1 * c - k2 * sn);
          keys[kdst + (size_t)r * HD + d + 32] = f2bf(k2 * c + k1 * sn);
        }
      }
    }
  } else {
    // V region -> valsT[(bkv*HD+d)*CTX + PP + perm(s)]
    const int b    = m0 >> 10;
    const int head = ((n0 - 2560) >> 6) + wn;
    const int sbase = (m0 - (b << 10)) + wm * 64;   // multiple of 64
    const size_t vrowb = (size_t)(b * KVH + head) * HD;
#pragma unroll
    for (int mt = 0; mt < 4; mt++) {
      const int pos = PP + sbase + ((mt >> 1) << 5) + ((mt & 1) << 2) + (g << 3);
#pragma unroll
      for (int nt = 0; nt < 4; nt++) {
        const int d = nt * 16 + n16;
        s4v o;
        o[0] = f2bf(acc[mt][nt][0]); o[1] = f2bf(acc[mt][nt][1]);
        o[2] = f2bf(acc[mt][nt][2]); o[3] = f2bf(acc[mt][nt][3]);
        *(s4v*)&vt[(vrowb + d) * CTX + pos] = o;
      }
    }
  }
}

// ---------------------------------------------------------------------------
// bf16 MFMA GEMM, BK=64, 2-phase double-buffered staging, split-K=2,
// atomic f32 accumulate (for O-proj).
// ---------------------------------------------------------------------------
__global__ __launch_bounds__(256) void gemm_bf16_sk(const short* __restrict__ A,
                                                    const short* __restrict__ Bw,
                                                    float* __restrict__ C,
                                                    int M, int N, int K) {
  __shared__ short As[2][8192];
  __shared__ short Bs[2][8192];
  const int tid  = threadIdx.x;
  const int wv   = tid >> 6, lane = tid & 63;
  const int wm   = wv & 1, wn = wv >> 1;
  const int n16  = lane & 15, g = lane >> 4;
  const int m0   = blockIdx.y * 128, n0 = blockIdx.x * 128;
  const int kh   = K >> 1;
  const int kbeg = blockIdx.z * kh;

  const int rr = tid >> 3;
  const int cc = ((tid & 7) ^ (rr & 7)) * 8;
  const short* pA = A  + (size_t)(m0 + rr) * K + kbeg + cc;
  const short* pB = Bw + (size_t)(n0 + rr) * K + kbeg + cc;

  auto stage = [&](int buf, int kofs) {
#pragma unroll
    for (int st = 0; st < 4; st++) {
      gl_lds16(pA + kofs + (size_t)st * 32 * K, &As[buf][(st * 256 + wv * 64) * 8]);
      gl_lds16(pB + kofs + (size_t)st * 32 * K, &Bs[buf][(st * 256 + wv * 64) * 8]);
    }
  };

  f4v acc[4][4] = {};
  stage(0, 0);
  int cur = 0;
  for (int k0 = 0; k0 < kh; k0 += 64) {
    __syncthreads();
    if (k0 + 64 < kh) stage(cur ^ 1, k0 + 64);

#pragma unroll
    for (int kk = 0; kk < 2; kk++) {
      s8v af[4], bf[4];
#pragma unroll
      for (int mt = 0; mt < 4; mt++)
        af[mt] = *(const s8v*)&As[cur][(wm * 64 + mt * 16 + n16) * 64 + (((kk << 2) | g) ^ (n16 & 7)) * 8];
#pragma unroll
      for (int nt = 0; nt < 4; nt++)
        bf[nt] = *(const s8v*)&Bs[cur][(wn * 64 + nt * 16 + n16) * 64 + (((kk << 2) | g) ^ (n16 & 7)) * 8];
#pragma unroll
      for (int mt = 0; mt < 4; mt++)
#pragma unroll
        for (int nt = 0; nt < 4; nt++)
          acc[mt][nt] = __builtin_amdgcn_mfma_f32_16x16x32_bf16(af[mt], bf[nt], acc[mt][nt], 0, 0, 0);
    }
    cur ^= 1;
  }

#pragma unroll
  for (int mt = 0; mt < 4; mt++)
#pragma unroll
    for (int nt = 0; nt < 4; nt++) {
      size_t base = (size_t)(m0 + wm * 64 + mt * 16 + g * 4) * N + n0 + wn * 64 + nt * 16 + n16;
#pragma unroll
      for (int r = 0; r < 4; r++)
        unsafeAtomicAdd(&C[base + (size_t)r * N], acc[mt][nt][r]);
    }
}

// ---------------------------------------------------------------------------
// MFMA flash attention (R1-measured structure: single-buffered, 16KB LDS)
// + T5 s_setprio around MFMA clusters. 1024 blocks (b,h,sblk), 4 waves,
// 16 q-rows/wave. exp2 softmax with no max-bias, cvt_pk bf16 packing,
// 4 parallel l-chains, gl_lds chunk-XOR swizzle (0-conflict).
// ---------------------------------------------------------------------------
__global__ __launch_bounds__(256) void attn_mfma(const short* __restrict__ qb,
                                                 const float* __restrict__ cosb,
                                                 const float* __restrict__ sinb,
                                                 const short* __restrict__ keys,
                                                 const short* __restrict__ valsT,
                                                 short* __restrict__ attn) {
  __shared__ short Ks[4096];    // K tile [key][dim] 64x64, chunk-swizzled
  __shared__ short VTs[4096];   // V^T tile [dim][permuted key], chunk-swizzled

  const int sblk = 15 - (blockIdx.x & 15);     // long blocks first
  const int h    = (blockIdx.x >> 4) & (H - 1);
  const int b    = blockIdx.x >> 9;
  const int kv   = h >> 2;
  const int sq0  = sblk * 64;
  const int kend = PP + sq0 + 64;

  const int tid  = threadIdx.x;
  const int w    = tid >> 6;
  const int lane = tid & 63;
  const int n    = lane & 15;
  const int g    = lane >> 4;

  const short* kbase = keys  + ((size_t)b * KVH + kv) * CTX * HD;
  const short* vtb   = valsT + ((size_t)b * KVH + kv) * (size_t)HD * CTX;

  // ---- Q frags: bf16 in, RoPE fused, scale = 0.125*log2(e) ----
  union { s4v h4[2]; s8v v; } qlo, qhi;
  {
    const size_t row = (size_t)b * S + sq0 + w * 16 + n;
    const short* qrow = qb + row * E + h * 64;
    const float* crow = cosb + row * HD;
    const float* srow = sinb + row * HD;
    const float SC = 0.18033688011112042f;   // 0.125 * log2(e)
    s8v q0 = *(const s8v*)&qrow[g * 8];
    s8v q1 = *(const s8v*)&qrow[32 + g * 8];
    float cc[8], ss[8];
    *(float4*)&cc[0] = *(const float4*)&crow[g * 8];
    *(float4*)&cc[4] = *(const float4*)&crow[g * 8 + 4];
    *(float4*)&ss[0] = *(const float4*)&srow[g * 8];
    *(float4*)&ss[4] = *(const float4*)&srow[g * 8 + 4];
#pragma unroll
    for (int j = 0; j < 8; j++) {
      float fl = bf2f(q0[j]), fh = bf2f(q1[j]);
      qlo.v[j] = f2bf((fl * cc[j] - fh * ss[j]) * SC);
      qhi.v[j] = f2bf((fh * cc[j] + fl * ss[j]) * SC);
    }
  }

  f4v O[4] = {{0,0,0,0},{0,0,0,0},{0,0,0,0},{0,0,0,0}};
  float la[4] = {0.f, 0.f, 0.f, 0.f};          // 4 parallel l-chains
  const int qp     = PP + sq0 + w * 16 + n;    // this lane's query position
  const int qmin_w = PP + sq0 + w * 16;        // wave's min query position

  // gl_lds staging: wave w stages rows w*8..w*8+7 (+32) of each 64x64 tile;
  // lane: row = w*8 + (lane>>3), chunk slot lane&7 holds global chunk slot^row
  const int lrow = lane >> 3;
  const int sw   = (lane & 7) ^ lrow;
  const short* kg0 = kbase + (size_t)(w * 8 + lrow) * HD + sw * 8;
  const short* kg1 = kg0 + 32 * HD;
  const short* vg0 = vtb + (size_t)(w * 8 + lrow) * CTX + sw * 8;
  const short* vg1 = vg0 + (size_t)32 * CTX;
  short* kl0 = Ks + w * 512;
  short* kl1 = Ks + 2048 + w * 512;
  short* vl0 = VTs + w * 512;
  short* vl1 = VTs + 2048 + w * 512;

  const int xsl = (g ^ (n & 7)) * 8;   // swizzled frag slot (lo); hi = ^32

  for (int k0 = 0; k0 < kend; k0 += 64) {
    __syncthreads();
    gl_lds16(kg0 + (size_t)k0 * HD, kl0);
    gl_lds16(kg1 + (size_t)k0 * HD, kl1);
    gl_lds16(vg0 + k0, vl0);
    gl_lds16(vg1 + k0, vl1);
    __syncthreads();

    if (k0 >= qmin_w + 16) continue;   // wave's K-range done (barriers aligned)

    // ---- S^T = K_tile @ Q^T (scores in log2 units) ----
    f4v sc[4];
    __builtin_amdgcn_s_setprio(1);
#pragma unroll
    for (int st = 0; st < 4; st++) {
      const short* krow = &Ks[(st * 16 + n) * 64];
      s8v alo = *(const s8v*)(krow + xsl);
      s8v ahi = *(const s8v*)(krow + (xsl ^ 32));
      f4v z = {0.f, 0.f, 0.f, 0.f};
      z = __builtin_amdgcn_mfma_f32_16x16x32_bf16(alo, qlo.v, z, 0, 0, 0);
      sc[st] = __builtin_amdgcn_mfma_f32_16x16x32_bf16(ahi, qhi.v, z, 0, 0, 0);
    }
    __builtin_amdgcn_s_setprio(0);

    // ---- causal mask near diagonal ----
    if (k0 + 63 > qmin_w) {
#pragma unroll
      for (int st = 0; st < 4; st++)
#pragma unroll
        for (int r = 0; r < 4; r++) {
          int kpos = k0 + st * 16 + g * 4 + r;
          if (kpos > qp) sc[st][r] = -3e38f;
        }
    }

    // ---- exp2 softmax; P^T packed into PV B-operand regs via cvt_pk ----
    union { unsigned u[4]; s8v v; } pb0, pb1;
#pragma unroll
    for (int st = 0; st < 4; st++) {
      float e0 = __builtin_amdgcn_exp2f(sc[st][0]);
      float e1 = __builtin_amdgcn_exp2f(sc[st][1]);
      float e2 = __builtin_amdgcn_exp2f(sc[st][2]);
      float e3 = __builtin_amdgcn_exp2f(sc[st][3]);
      la[0] += e0; la[1] += e1; la[2] += e2; la[3] += e3;
      unsigned w0, w1;
      asm("v_cvt_pk_bf16_f32 %0, %1, %2" : "=v"(w0) : "v"(e0), "v"(e1));
      asm("v_cvt_pk_bf16_f32 %0, %1, %2" : "=v"(w1) : "v"(e2), "v"(e3));
      if (st < 2) { pb0.u[st * 2] = w0; pb0.u[st * 2 + 1] = w1; }
      else        { pb1.u[(st - 2) * 2] = w0; pb1.u[(st - 2) * 2 + 1] = w1; }
    }

    // ---- O^T += V^T @ P ----
    __builtin_amdgcn_s_setprio(1);
#pragma unroll
    for (int dg = 0; dg < 4; dg++) {
      const short* vr = &VTs[(dg * 16 + n) * 64];
      s8v va = *(const s8v*)(vr + xsl);
      s8v vx = *(const s8v*)(vr + (xsl ^ 32));
      O[dg] = __builtin_amdgcn_mfma_f32_16x16x32_bf16(va, pb0.v, O[dg], 0, 0, 0);
      O[dg] = __builtin_amdgcn_mfma_f32_16x16x32_bf16(vx, pb1.v, O[dg], 0, 0, 0);
    }
    __builtin_amdgcn_s_setprio(0);
  }

  // ---- reduce l across 4 g-lanes per query, normalize, store ----
  float l = (la[0] + la[1]) + (la[2] + la[3]);
  l += __shfl_xor(l, 16);
  l += __shfl_xor(l, 32);
  const float rl = 1.f / l;
  short* orow = attn + ((size_t)b * S + sq0 + w * 16 + n) * E + h * 64;
#pragma unroll
  for (int dg = 0; dg < 4; dg++) {
    s4v o;
    o[0] = f2bf(O[dg][0] * rl); o[1] = f2bf(O[dg][1] * rl);
    o[2] = f2bf(O[dg][2] * rl); o[3] = f2bf(O[dg][3] * rl);
    *(s4v*)&orow[dg * 16 + g * 4] = o;
  }
}

// ---------------------------------------------------------------------------
extern "C" void kernel_launch(void* const* d_in, const int* in_sizes, int n_in,
                              void* d_out, int out_size, void* d_ws, size_t ws_size,
                              hipStream_t stream) {
  const float* x       = (const float*)d_in[0];
  const float* cosb    = (const float*)d_in[1];
  const float* sinb    = (const float*)d_in[2];
  const float* cache_k = (const float*)d_in[4];
  const float* cache_v = (const float*)d_in[5];
  const float* Wq      = (const float*)d_in[6];
  const float* Wk      = (const float*)d_in[7];
  const float* Wv      = (const float*)d_in[8];
  const float* Wo      = (const float*)d_in[9];
  float* out = (float*)d_out;

  short* xb    = (short*)d_ws;                 // 4,194,304
  short* wqkv  = xb + 4194304;                 // 6,291,456
  short* wob   = wqkv + 6291456;               // 4,194,304
  short* keysb = wob + 4194304;                // 2,097,152
  short* valsT = keysb + 2097152;              // 2,097,152 (permuted V^T)
  short* aout  = valsT + 2097152;              // 4,194,304
  short* qb    = aout + 4194304;               // 4,194,304  (~55 MB total)

  dim3 blk(256);

  // 1) converts qkv_gemm depends on (x, Wq, Wk, Wv)
  prep<<<5120, blk, 0, stream>>>(x, Wq, Wk, Wv, xb, wqkv);

  // 2) fused QKV projection (384 GEMM blocks) + aux prep (3840 blocks:
  //    Wo convert, cache_k, vT_old, zero-out) filling idle CUs
  qkv_gemm<<<4224, blk, 0, stream>>>(xb, wqkv, cosb, sinb, Wo, cache_k, cache_v,
                                     qb, keysb, valsT, wob, (float4*)out);

  // 3) attention (R1 structure + setprio) -> bf16 (B,S,E)
  attn_mfma<<<B * H * (S / 64), blk, 0, stream>>>(qb, cosb, sinb, keysb, valsT, aout);

  // 4) output projection, split-K=2 -> f32 out (zeroed in qkv aux)
  gemm_bf16_sk<<<dim3(E / 128, (B * S) / 128, 2), blk, 0, stream>>>(aout, wob, out, B * S, E, E);
}